// Round 4
// baseline (64.192 us; speedup 1.0000x reference)
//
#include <hip/hip_runtime.h>

#define N_ROWS 131072
#define DIM 64
#define KNEG 1024
#define FEPS 1e-10f
#define LOG2E 1.4426950408889634f
#define HSLOTS 2048
#define CPI 64                  // cols per outer iter
#define OUTER (KNEG / CPI)      // 16
#define CSTR 72                 // shorts per col in LDS (144 B padded)

typedef __attribute__((ext_vector_type(8))) short bf16x8;
typedef __attribute__((ext_vector_type(4))) float f32x4;

__device__ __forceinline__ unsigned short f2bf(float x) {
    unsigned int u = __float_as_uint(x);
    unsigned int r = (u + 0x7fffu + ((u >> 16) & 1u)) >> 16;
    return (unsigned short)r;
}

#if __has_builtin(__builtin_amdgcn_exp2f)
__device__ __forceinline__ float fexp2(float x) { return __builtin_amdgcn_exp2f(x); }
#else
__device__ __forceinline__ float fexp2(float x) {
    float r; asm("v_exp_f32 %0, %1\ns_nop 1" : "=v"(r) : "v"(x)); return r;
}
#endif

__device__ __forceinline__ bf16x8 cvt8(float4 u, float4 v) {
    bf16x8 r;
    r[0] = (short)f2bf(u.x * LOG2E); r[1] = (short)f2bf(u.y * LOG2E);
    r[2] = (short)f2bf(u.z * LOG2E); r[3] = (short)f2bf(u.w * LOG2E);
    r[4] = (short)f2bf(v.x * LOG2E); r[5] = (short)f2bf(v.y * LOG2E);
    r[6] = (short)f2bf(v.z * LOG2E); r[7] = (short)f2bf(v.w * LOG2E);
    return r;
}

// ---------------------------------------------------------------------------
// prep_k: blocks 0..63 gather e_neg -> bf16 packed [col][k] (64 CUs, latency
// spread); block 64: G, lf[c] = (-log(q_c+eps)-G)*log2e, collision hash.
// ---------------------------------------------------------------------------
__global__ __launch_bounds__(256) void prep_k(
    const float* __restrict__ emb, const int* __restrict__ sidx,
    const float* __restrict__ probs,
    unsigned short* __restrict__ enegPK, float* __restrict__ lf,
    float* __restrict__ gv, int* __restrict__ hkey, float* __restrict__ hval)
{
    const int tid = threadIdx.x;
    if (blockIdx.x < 64) {
        const int gid = blockIdx.x * 256 + tid;    // 0..16383
        const int col = gid >> 4;
        const int j   = gid & 15;
        const int c = sidx[col];
        const float4 v = *(const float4*)(emb + (size_t)c * DIM + j * 4);
        unsigned int lo = (unsigned int)f2bf(v.x) | ((unsigned int)f2bf(v.y) << 16);
        unsigned int hi = (unsigned int)f2bf(v.z) | ((unsigned int)f2bf(v.w) << 16);
        ((uint2*)enegPK)[(size_t)col * 16 + j] = make_uint2(lo, hi);
    } else {
        for (int s = tid; s < HSLOTS; s += 256) { hkey[s] = -1; hval[s] = 0.0f; }
        float L[4];
        float m = -1e30f;
        int cs[4];
#pragma unroll
        for (int i = 0; i < 4; ++i) {
            cs[i] = sidx[tid * 4 + i];
            L[i] = logf(probs[cs[i]] + FEPS);
            m = fmaxf(m, -L[i]);
        }
        __shared__ float red[256];
        red[tid] = m;
        __syncthreads();
        for (int s2 = 128; s2 > 0; s2 >>= 1) {
            if (tid < s2) red[tid] = fmaxf(red[tid], red[tid + s2]);
            __syncthreads();
        }
        const float G = red[0] + 2.0f;
        if (tid == 0) gv[0] = G;
#pragma unroll
        for (int i = 0; i < 4; ++i) {
            const float lfv = (-L[i] - G) * LOG2E;
            lf[tid * 4 + i] = lfv;
            const float fc = exp2f(lfv);
            unsigned int slot = ((unsigned int)cs[i] * 2654435761u) & (HSLOTS - 1);
            for (int it = 0; it < HSLOTS; ++it) {
                int old = atomicCAS(&hkey[slot], -1, cs[i]);
                if (old == -1 || old == cs[i]) { atomicAdd(&hval[slot], fc); break; }
                slot = (slot + 1) & (HSLOTS - 1);
            }
        }
    }
}

// ---------------------------------------------------------------------------
// main_k: 4 waves/block, 32 rows/wave, 64-col double-buffered LDS tiles,
// ONE barrier per outer iter. acc init = lf_col -> per element 1 exp2 + 1 add.
// LDS 22.5 KB/block -> 4 blocks/CU (16 waves/CU).
// ---------------------------------------------------------------------------
__global__ __launch_bounds__(256, 4) void main_k(
    const float* __restrict__ hidden, const int* __restrict__ y,
    const float* __restrict__ emb, const float* __restrict__ probs,
    const unsigned short* __restrict__ enegPK, const float* __restrict__ lf,
    const float* __restrict__ gv, const int* __restrict__ hkey,
    const float* __restrict__ hval,
    float* __restrict__ pv, float* __restrict__ pw)
{
    __shared__ __align__(16) short bt[2][CPI * CSTR];    // 18432 B
    __shared__ float lf_lds[KNEG];                        //  4096 B

    const int tid  = threadIdx.x;
    const int wid  = tid >> 6;
    const int lane = tid & 63;
    const int quad = lane >> 4;
    const int l15  = lane & 15;

    const int row0 = (blockIdx.x * 4 + wid) * 32;
    const int r0 = row0 + l15;
    const int r1 = r0 + 16;

    const int y0 = y[r0];
    const int y1 = y[r1];

    for (int i = tid; i < KNEG; i += 256) lf_lds[i] = lf[i];

    // preload B tile 0: 512 uint4 staged by 256 threads (2 each)
    const uint4* g4 = (const uint4*)enegPK;      // 8 uint4 per col, col-major
    const int cw0 = tid >> 3;                     // col 0..31
    const int cw1 = (tid + 256) >> 3;             // col 32..63
    const int ow  = tid & 7;
    {
        uint4 u0 = g4[tid], u1 = g4[tid + 256];
        *((uint4*)(&bt[0][cw0 * CSTR]) + ow) = u0;
        *((uint4*)(&bt[0][cw1 * CSTR]) + ow) = u1;
    }

    // hidden rows (f32)
    const float* hp0 = hidden + (size_t)r0 * DIM + quad * 8;
    const float* hp1 = hidden + (size_t)r1 * DIM + quad * 8;
    const float4 a0 = *(const float4*)(hp0 + 0);
    const float4 a1 = *(const float4*)(hp0 + 4);
    const float4 a2 = *(const float4*)(hp0 + 32);
    const float4 a3 = *(const float4*)(hp0 + 36);
    const float4 c0 = *(const float4*)(hp1 + 0);
    const float4 c1 = *(const float4*)(hp1 + 4);
    const float4 c2 = *(const float4*)(hp1 + 32);
    const float4 c3 = *(const float4*)(hp1 + 36);

    // positive logit dots (f32, exact)
    const float* pe0 = emb + (size_t)y0 * DIM + quad * 8;
    const float* pe1 = emb + (size_t)y1 * DIM + quad * 8;
    const float4 e0 = *(const float4*)(pe0 + 0);
    const float4 e1 = *(const float4*)(pe0 + 4);
    const float4 e2 = *(const float4*)(pe0 + 32);
    const float4 e3 = *(const float4*)(pe0 + 36);
    const float4 g0 = *(const float4*)(pe1 + 0);
    const float4 g1 = *(const float4*)(pe1 + 4);
    const float4 g2 = *(const float4*)(pe1 + 32);
    const float4 g3 = *(const float4*)(pe1 + 36);
    float pd0 = a0.x*e0.x + a0.y*e0.y + a0.z*e0.z + a0.w*e0.w
              + a1.x*e1.x + a1.y*e1.y + a1.z*e1.z + a1.w*e1.w
              + a2.x*e2.x + a2.y*e2.y + a2.z*e2.z + a2.w*e2.w
              + a3.x*e3.x + a3.y*e3.y + a3.z*e3.z + a3.w*e3.w;
    float pd1 = c0.x*g0.x + c0.y*g0.y + c0.z*g0.z + c0.w*g0.w
              + c1.x*g1.x + c1.y*g1.y + c1.z*g1.z + c1.w*g1.w
              + c2.x*g2.x + c2.y*g2.y + c2.z*g2.z + c2.w*g2.w
              + c3.x*g3.x + c3.y*g3.y + c3.z*g3.z + c3.w*g3.w;
    pd0 += __shfl_xor(pd0, 16, 64); pd0 += __shfl_xor(pd0, 32, 64);
    pd1 += __shfl_xor(pd1, 16, 64); pd1 += __shfl_xor(pd1, 32, 64);

    const bf16x8 h00 = cvt8(a0, a1), h01 = cvt8(a2, a3);
    const bf16x8 h10 = cvt8(c0, c1), h11 = cvt8(c2, c3);

    __syncthreads();

    float s00 = 0.f, s01 = 0.f, s02 = 0.f, s03 = 0.f;
    float s10 = 0.f, s11 = 0.f, s12 = 0.f, s13 = 0.f;
    int p = 0;

    for (int t = 0; t < OUTER; ++t) {
        uint4 u0, u1;
        const bool has = (t + 1 < OUTER);
        if (has) {                          // issue next-tile loads EARLY
            const uint4* gs = g4 + (t + 1) * 512;
            u0 = gs[tid]; u1 = gs[tid + 256];
        }
#pragma unroll
        for (int tt = 0; tt < CPI / 16; ++tt) {
            const short* bp = &bt[p][(tt * 16 + l15) * CSTR + quad * 8];
            const bf16x8 b0 = *(const bf16x8*)bp;
            const bf16x8 b1 = *(const bf16x8*)(bp + 32);
            const float lfv = lf_lds[t * CPI + tt * 16 + l15];
            f32x4 acc0 = {lfv, lfv, lfv, lfv};
            acc0 = __builtin_amdgcn_mfma_f32_16x16x32_bf16(h00, b0, acc0, 0, 0, 0);
            acc0 = __builtin_amdgcn_mfma_f32_16x16x32_bf16(h01, b1, acc0, 0, 0, 0);
            f32x4 acc1 = {lfv, lfv, lfv, lfv};
            acc1 = __builtin_amdgcn_mfma_f32_16x16x32_bf16(h10, b0, acc1, 0, 0, 0);
            acc1 = __builtin_amdgcn_mfma_f32_16x16x32_bf16(h11, b1, acc1, 0, 0, 0);
            s00 += fexp2(acc0[0]); s01 += fexp2(acc0[1]);
            s02 += fexp2(acc0[2]); s03 += fexp2(acc0[3]);
            s10 += fexp2(acc1[0]); s11 += fexp2(acc1[1]);
            s12 += fexp2(acc1[2]); s13 += fexp2(acc1[3]);
        }
        if (has) {                          // write-late into the other buffer
            *((uint4*)(&bt[p ^ 1][cw0 * CSTR]) + ow) = u0;
            *((uint4*)(&bt[p ^ 1][cw1 * CSTR]) + ow) = u1;
        }
        __syncthreads();                    // ONE barrier per iter
        p ^= 1;
    }

    // reduce col-slices across the 16 lanes of each quad
#pragma unroll
    for (int m = 8; m > 0; m >>= 1) {
        s00 += __shfl_xor(s00, m, 64); s01 += __shfl_xor(s01, m, 64);
        s02 += __shfl_xor(s02, m, 64); s03 += __shfl_xor(s03, m, 64);
        s10 += __shfl_xor(s10, m, 64); s11 += __shfl_xor(s11, m, 64);
        s12 += __shfl_xor(s12, m, 64); s13 += __shfl_xor(s13, m, 64);
    }
    // row (l15)'s sum lives in quad l15>>2, reg l15&3
    float sa0 = (lane & 1) ? s01 : s00;
    float sb0 = (lane & 1) ? s03 : s02;
    float sv0 = (lane & 2) ? sb0 : sa0;
    sv0 = __shfl(sv0, ((l15 >> 2) << 4) + l15, 64);
    float sa1 = (lane & 1) ? s11 : s10;
    float sb1 = (lane & 1) ? s13 : s12;
    float sv1 = (lane & 2) ? sb1 : sa1;
    sv1 = __shfl(sv1, ((l15 >> 2) << 4) + l15, 64);

    const float G = gv[0];
    float v = 0.f, ww = 0.f;
    {
        const float pos = pd0 - logf(probs[y0] + FEPS);
        float H = 0.0f;
        unsigned int slot = ((unsigned int)y0 * 2654435761u) & (HSLOTS - 1);
        for (int it = 0; it < HSLOTS; ++it) {
            const int k = hkey[slot];
            if (k == y0) { H = hval[slot]; break; }
            if (k == -1) break;
            slot = (slot + 1) & (HSLOTS - 1);
        }
        float sneg = fmaxf(sv0 - exp2f(pd0 * LOG2E) * H, 0.0f);
        const float M = fmaxf(G, pos);
        const float lse = M + logf(exp2f((pos - M) * LOG2E) + sneg * exp2f((G - M) * LOG2E));
        const float w = (y0 != 0) ? 1.0f : 0.0f;
        v += (lse - pos) * w; ww += w;
    }
    {
        const float pos = pd1 - logf(probs[y1] + FEPS);
        float H = 0.0f;
        unsigned int slot = ((unsigned int)y1 * 2654435761u) & (HSLOTS - 1);
        for (int it = 0; it < HSLOTS; ++it) {
            const int k = hkey[slot];
            if (k == y1) { H = hval[slot]; break; }
            if (k == -1) break;
            slot = (slot + 1) & (HSLOTS - 1);
        }
        float sneg = fmaxf(sv1 - exp2f(pd1 * LOG2E) * H, 0.0f);
        const float M = fmaxf(G, pos);
        const float lse = M + logf(exp2f((pos - M) * LOG2E) + sneg * exp2f((G - M) * LOG2E));
        const float w = (y1 != 0) ? 1.0f : 0.0f;
        v += (lse - pos) * w; ww += w;
    }
#pragma unroll
    for (int m = 8; m > 0; m >>= 1) {
        v  += __shfl_xor(v, m, 64);
        ww += __shfl_xor(ww, m, 64);
    }
    if (lane == 0) {
        const int wgid = blockIdx.x * 4 + wid;
        pv[wgid] = v;
        pw[wgid] = ww;
    }
}

__global__ __launch_bounds__(256) void fin_k(
    const float* __restrict__ pv, const float* __restrict__ pw,
    float* __restrict__ out)
{
    const int tid = threadIdx.x;
    double av = 0.0, aw = 0.0;
    for (int i = tid; i < N_ROWS / 32; i += 256) { av += pv[i]; aw += pw[i]; }
    __shared__ double rv[256], rw[256];
    rv[tid] = av; rw[tid] = aw;
    __syncthreads();
    for (int s2 = 128; s2 > 0; s2 >>= 1) {
        if (tid < s2) { rv[tid] += rv[tid + s2]; rw[tid] += rw[tid + s2]; }
        __syncthreads();
    }
    if (tid == 0) {
        double c = rw[0] < 1.0 ? 1.0 : rw[0];
        out[0] = (float)(rv[0] / c);
    }
}

extern "C" void kernel_launch(void* const* d_in, const int* in_sizes, int n_in,
                              void* d_out, int out_size, void* d_ws, size_t ws_size,
                              hipStream_t stream) {
    const float* hidden = (const float*)d_in[0];
    const int*   yv     = (const int*)d_in[1];
    const int*   sidx   = (const int*)d_in[2];
    const float* emb    = (const float*)d_in[3];
    const float* probs  = (const float*)d_in[4];
    float* out = (float*)d_out;

    char* ws = (char*)d_ws;
    unsigned short* enegPK = (unsigned short*)(ws);          // 131072 B
    float* lf   = (float*)(ws + 131072);                     //   4096 B
    float* gv   = (float*)(ws + 135168);                     //    256 B
    int*   hkey = (int*)(ws + 135424);                       //   8192 B
    float* hval = (float*)(ws + 143616);                     //   8192 B
    float* pv   = (float*)(ws + 151808);                     //  16384 B
    float* pw   = (float*)(ws + 168192);                     //  16384 B

    prep_k<<<65, 256, 0, stream>>>(emb, sidx, probs, enegPK, lf, gv, hkey, hval);
    main_k<<<N_ROWS / 128, 256, 0, stream>>>(hidden, yv, emb, probs, enegPK,
                                             lf, gv, hkey, hval, pv, pw);
    fin_k<<<1, 256, 0, stream>>>(pv, pw, out);
}